// Round 7
// baseline (170.669 us; speedup 1.0000x reference)
//
#include <hip/hip_runtime.h>
#include <stdint.h>

// Problem constants (from reference setup_inputs)
constexpr int B  = 32;
constexpr int H  = 256;
constexpr int W  = 1216;
constexpr int HW = H * W;            // 311296 (divisible by 4)
constexpr int N  = B * HW;           // 9961472 elements in gt / weight_map
constexpr int NCHUNK  = N / 4;       // 2490368 float4 chunks
constexpr int BLOCKSZ = 256;
constexpr int GRID    = 1024;        // 4 blocks/CU
constexpr int CSTRIDE = GRID * BLOCKSZ;   // 262144; blocks<512: 10 iters, else 9

constexpr int NSLOT = 16;

// s_waitcnt imms: vmcnt in bits[3:0] (lo) / [15:14] (hi), expcnt [6:4], lgkmcnt [11:8].
// Wait ONLY on vmcnt: lgkm=15, exp=7.
#define WAIT_VM6 0xF76
#define WAIT_VM3 0xF73
#define WAIT_VM0 0xF70

typedef float vfloat4 __attribute__((ext_vector_type(4)));
typedef int   vint4   __attribute__((ext_vector_type(4)));

// CK-style address-space casts for global_load_lds (battle-tested pattern)
template <typename T>
__device__ __forceinline__ const __attribute__((address_space(1))) T* to_as1(const T* p) {
    return reinterpret_cast<const __attribute__((address_space(1))) T*>(
        reinterpret_cast<uintptr_t>(p));
}
template <typename T>
__device__ __forceinline__ __attribute__((address_space(3))) T* to_as3(T* p) {
    return reinterpret_cast<__attribute__((address_space(3))) T*>(
        reinterpret_cast<uintptr_t>(p));
}

__device__ __forceinline__ void accum(const vfloat4& p, const vfloat4& g,
                                      const vint4& w, float* sum, int* cnt)
{
    const float e0 = p.x - g.x, e1 = p.y - g.y;
    const float e2 = p.z - g.z, e3 = p.w - g.w;
    const float s0 = e0 * e0, s1 = e1 * e1, s2 = e2 * e2, s3 = e3 * e3;
#pragma unroll
    for (int j = 0; j < 8; ++j) {
        const int bin = j + 1;
        sum[j] += (w.x == bin) ? s0 : 0.f;
        cnt[j] += (w.x == bin) ? 1 : 0;
        sum[j] += (w.y == bin) ? s1 : 0.f;
        cnt[j] += (w.y == bin) ? 1 : 0;
        sum[j] += (w.z == bin) ? s2 : 0.f;
        cnt[j] += (w.z == bin) ? 1 : 0;
        sum[j] += (w.w == bin) ? s3 : 0.f;
        cnt[j] += (w.w == bin) ? 1 : 0;
    }
}

__global__ __launch_bounds__(BLOCKSZ) void seg_mse_kernel(
    const float* __restrict__ pred,
    const float* __restrict__ gt,
    const int*   __restrict__ wm,
    float* __restrict__ part)
{
    // Triple-buffered direct-to-LDS staging. 3 bufs x 3 arrays x 4 KB = 36 KB.
    // Each wave deposits into and reads back ONLY its own 1 KB segment of each
    // buffer => no __syncthreads in the loop; waves self-sync via vmcnt.
    __shared__ vfloat4 bufP[3][BLOCKSZ];
    __shared__ vfloat4 bufG[3][BLOCKSZ];
    __shared__ vint4   bufW[3][BLOCKSZ];

    const int tid   = threadIdx.x;
    const int wave  = tid >> 6;          // wave-uniform
    const int start = blockIdx.x * BLOCKSZ + tid;
    const int niter = (blockIdx.x < 512) ? 10 : 9;   // exact cover of NCHUNK

    // Issue one iteration's staging: 3 global_load_lds_dwordx4 per wave
    // (per-lane global addr; LDS dest = wave-uniform base + lane*16).
    auto issue = [&](int i, int buf) {
        const int c  = start + i * CSTRIDE;
        const int i0 = c * 4;
        const int b  = i0 / HW;          // batch (magic-mul)
        __builtin_amdgcn_global_load_lds(
            (const __attribute__((address_space(1))) void*)to_as1(pred + (i0 + b * HW)),
            (__attribute__((address_space(3))) void*)to_as3(&bufP[buf][wave * 64]),
            16, 0, 0);
        __builtin_amdgcn_global_load_lds(
            (const __attribute__((address_space(1))) void*)to_as1(gt + i0),
            (__attribute__((address_space(3))) void*)to_as3(&bufG[buf][wave * 64]),
            16, 0, 0);
        __builtin_amdgcn_global_load_lds(
            (const __attribute__((address_space(1))) void*)to_as1(wm + i0),
            (__attribute__((address_space(3))) void*)to_as3(&bufW[buf][wave * 64]),
            16, 0, 0);
    };

    float sum[8] = {0.f, 0.f, 0.f, 0.f, 0.f, 0.f, 0.f, 0.f};
    int   cnt[8] = {0, 0, 0, 0, 0, 0, 0, 0};

    // Prologue: 2 iterations in flight (niter >= 9 always).
    issue(0, 0);
    issue(1, 1);

    for (int i = 0; i < niter; ++i) {
        const int buf = i % 3;
        if (i + 2 < niter) {
            issue(i + 2, (i + 2) % 3);           // 9 outstanding loads
            __builtin_amdgcn_s_waitcnt(WAIT_VM6); // wait iter i's 3 done
        } else if (i + 1 < niter) {
            __builtin_amdgcn_s_waitcnt(WAIT_VM3);
        } else {
            __builtin_amdgcn_s_waitcnt(WAIT_VM0);
        }
        // Keep the LDS reads below the waitcnt (optimizer fence, 0 instrs).
        asm volatile("" ::: "memory");

        const vfloat4 p = bufP[buf][tid];   // ds_read_b128, own wave's segment
        const vfloat4 g = bufG[buf][tid];
        const vint4   w = bufW[buf][tid];
        accum(p, g, w, sum, cnt);
        // accum uses p/g/w => lgkmcnt drained before the next issue() overwrites
        // this buffer (WAR on buf happens 2 iterations later in program order).
    }

    // wave (64-lane) butterfly reduction of all 16 partials
    float fcnt[8];
#pragma unroll
    for (int j = 0; j < 8; ++j) fcnt[j] = (float)cnt[j];
#pragma unroll
    for (int j = 0; j < 8; ++j) {
#pragma unroll
        for (int off = 32; off > 0; off >>= 1) {
            sum[j]  += __shfl_down(sum[j], off);
            fcnt[j] += __shfl_down(fcnt[j], off);
        }
    }

    // cross-wave reduction in LDS (reuse is fine: after __syncthreads)
    __shared__ float lsum[4][8];
    __shared__ float lcnt[4][8];
    const int lane = tid & 63;
    if (lane == 0) {
#pragma unroll
        for (int j = 0; j < 8; ++j) {
            lsum[wave][j] = sum[j];
            lcnt[wave][j] = fcnt[j];
        }
    }
    __syncthreads();

    // 16 plain coalesced stores per block (one 64B segment); NO atomics/fences.
    if (tid < 8) {
        const int j = tid;
        part[blockIdx.x * NSLOT + j] =
            lsum[0][j] + lsum[1][j] + lsum[2][j] + lsum[3][j];
    } else if (tid < 16) {
        const int j = tid - 8;
        part[blockIdx.x * NSLOT + 8 + j] =
            lcnt[0][j] + lcnt[1][j] + lcnt[2][j] + lcnt[3][j];
    }
}

// Single-block reduction of GRID x 16 partials (64 KB, L2-resident).
__global__ __launch_bounds__(1024) void finalize_kernel(
    const float* __restrict__ part,
    float* __restrict__ out)
{
    const int tid = threadIdx.x;
    const int j   = tid & 15;        // slot
    const int g   = tid >> 4;        // group 0..63
    float v = 0.f;
#pragma unroll
    for (int i = 0; i < GRID / 64; ++i) {
        v += part[(g + 64 * i) * NSLOT + j];
    }
    // combine groups within the wave: lanes differing in bits 4,5 share slot j
    v += __shfl_xor(v, 16);
    v += __shfl_xor(v, 32);

    // cross-wave: 16 waves each contribute one value per slot
    __shared__ float wsum[16][16];
    const int wave = tid >> 6;
    const int lane = tid & 63;
    if (lane < 16) wsum[wave][lane] = v;
    __syncthreads();

    __shared__ float fin[16];
    if (tid < 16) {
        float t = 0.f;
#pragma unroll
        for (int w = 0; w < 16; ++w) t += wsum[w][tid];
        fin[tid] = t;
    }
    __syncthreads();

    if (tid == 0) {
        float total = 0.f;
#pragma unroll
        for (int j2 = 0; j2 < 8; ++j2) {
            total += fin[j2] / fmaxf(fin[8 + j2], 1.f);
        }
        out[0] = total * (1.f / 8.f);
    }
}

extern "C" void kernel_launch(void* const* d_in, const int* in_sizes, int n_in,
                              void* d_out, int out_size, void* d_ws, size_t ws_size,
                              hipStream_t stream)
{
    const float* pred = (const float*)d_in[0];  // [32,2,256,1216] f32
    const float* gt   = (const float*)d_in[1];  // [32,1,256,1216] f32
    const int*   wm   = (const int*)d_in[2];    // [32,1,256,1216] i32
    float* part = (float*)d_ws;                 // GRID*16 floats = 64 KB

    // No memset needed: every part[] slot is written by the main kernel.
    seg_mse_kernel<<<GRID, BLOCKSZ, 0, stream>>>(pred, gt, wm, part);
    finalize_kernel<<<1, 1024, 0, stream>>>(part, (float*)d_out);
}